// Round 1
// baseline (651.326 us; speedup 1.0000x reference)
//
#include <hip/hip_runtime.h>
#include <hip/hip_bf16.h>

typedef __bf16 bf16x8 __attribute__((ext_vector_type(8)));
typedef float f32x4 __attribute__((ext_vector_type(4)));
typedef unsigned short ushort8 __attribute__((ext_vector_type(8)));

static_assert(sizeof(bf16x8) == 16, "bf16x8 must be 16B");

#define NH 12
#define SEQ 2048
#define DM 768
#define DH 64
#define NB 2

static __device__ __forceinline__ unsigned short f2bf(float f) {
    __hip_bfloat16 h = __float2bfloat16(f);
    return __builtin_bit_cast(unsigned short, h);
}
static __device__ __forceinline__ bf16x8 ld_bf8(const unsigned short* p) {
    ushort8 u = *(const ushort8*)p;
    return __builtin_bit_cast(bf16x8, u);
}

// ---------------------------------------------------------------------------
// Kernel D: weight transpose + bf16 convert.
// Wt[p][h][n=dh][k=dm] = W_p[h][k][n];  Wot[h][m][d] = W_O[h][d][m]
// ---------------------------------------------------------------------------
__global__ __launch_bounds__(256) void kprep(
    const float* __restrict__ WQ, const float* __restrict__ WK,
    const float* __restrict__ WV, const float* __restrict__ WO,
    unsigned short* __restrict__ Wt, unsigned short* __restrict__ Wot)
{
    __shared__ __align__(16) unsigned short T[64 * 72];
    int bid = blockIdx.x;              // 576 = 4 tensors * 12 h * 12 tiles
    int tensor = bid / 144;
    int rem = bid % 144;
    int h = rem / 12, tile = rem % 12;
    const float* src; unsigned short* dst; int R, C, r0, c0;
    if (tensor < 3) {
        src = (tensor == 0 ? WQ : tensor == 1 ? WK : WV) + (size_t)h * DM * DH;
        dst = Wt + ((size_t)tensor * NH + h) * DH * DM;
        R = DM; C = DH; r0 = tile * 64; c0 = 0;
    } else {
        src = WO + (size_t)h * DH * DM;
        dst = Wot + (size_t)h * DM * DH;
        R = DH; C = DM; r0 = 0; c0 = tile * 64;
    }
    int t = threadIdx.x;
    int rr = t >> 2, cc0 = (t & 3) * 16;
    const float* sp = src + (size_t)(r0 + rr) * C + c0 + cc0;
#pragma unroll
    for (int i = 0; i < 4; i++) {
        float4 v = *(const float4*)(sp + 4 * i);
        T[(cc0 + 4 * i + 0) * 72 + rr] = f2bf(v.x);
        T[(cc0 + 4 * i + 1) * 72 + rr] = f2bf(v.y);
        T[(cc0 + 4 * i + 2) * 72 + rr] = f2bf(v.z);
        T[(cc0 + 4 * i + 3) * 72 + rr] = f2bf(v.w);
    }
    __syncthreads();
    int cc = t >> 2, ch = t & 3;
    ushort8 o0 = *(const ushort8*)&T[cc * 72 + ch * 16];
    ushort8 o1 = *(const ushort8*)&T[cc * 72 + ch * 16 + 8];
    unsigned short* dp = dst + (size_t)(c0 + cc) * R + r0 + ch * 16;
    *(ushort8*)dp = o0;
    *(ushort8*)(dp + 8) = o1;
}

// ---------------------------------------------------------------------------
// Kernel A: QKV projection + bias + rotary; Q,K -> [b][h][s][d] bf16,
// V -> transposed [b][h][d][s] bf16.
// ---------------------------------------------------------------------------
__global__ __launch_bounds__(256) void kproj(
    const float* __restrict__ Xq, const float* __restrict__ Xk,
    const float* __restrict__ Xv, const unsigned short* __restrict__ Wt,
    const float* __restrict__ bQ, const float* __restrict__ bK,
    const float* __restrict__ bV,
    unsigned short* __restrict__ Qw, unsigned short* __restrict__ Kw,
    unsigned short* __restrict__ Vtw)
{
    __shared__ __align__(16) unsigned short sm[64 * 72];
    int bid = blockIdx.x;              // 2304 = 3 * 2 * 12 * 32
    int p  = bid / 768;
    int b  = (bid / 384) & 1;
    int h  = (bid / 32) % 12;
    int st = bid & 31;
    const float* X = p == 0 ? Xq : (p == 1 ? Xk : Xv);
    int t = threadIdx.x;
    int w = t >> 6, lane = t & 63, l = lane & 15, quad = lane >> 4;

    // A-fragment source: row (16w + l) of this s-tile, direct from global fp32
    const float* xrow = X + (((size_t)(b * SEQ + st * 64 + 16 * w + l)) * NH + h) * DM + quad * 8;
    const unsigned short* wbase = Wt + ((size_t)(p * NH + h)) * DH * DM;

    f32x4 acc[4] = {};
    for (int k0 = 0; k0 < DM; k0 += 32) {
        float4 f0 = *(const float4*)(xrow + k0);
        float4 f1 = *(const float4*)(xrow + k0 + 4);
        ushort8 u;
        u[0] = f2bf(f0.x); u[1] = f2bf(f0.y); u[2] = f2bf(f0.z); u[3] = f2bf(f0.w);
        u[4] = f2bf(f1.x); u[5] = f2bf(f1.y); u[6] = f2bf(f1.z); u[7] = f2bf(f1.w);
        bf16x8 a = __builtin_bit_cast(bf16x8, u);
#pragma unroll
        for (int nt = 0; nt < 4; nt++) {
            bf16x8 bf = ld_bf8(wbase + ((size_t)(16 * nt + l)) * DM + k0 + quad * 8);
            acc[nt] = __builtin_amdgcn_mfma_f32_16x16x32_bf16(a, bf, acc[nt], 0, 0, 0);
        }
    }

    const float* bias = p == 0 ? bQ : (p == 1 ? bK : bV);
#pragma unroll
    for (int nt = 0; nt < 4; nt++) {
        float bv = bias[h * DH + 16 * nt + l];
#pragma unroll
        for (int r = 0; r < 4; r++) acc[nt][r] += bv;
    }

    if (p < 2) {
        // rotary: d and d+32 live in acc[nt] and acc[nt+2] at the same lane/reg
        const float L2B = 13.287712379549449f;   // log2(10000)
        float inv1 = exp2f(-((float)l)        * (L2B / 32.0f));
        float inv2 = exp2f(-((float)(l + 16)) * (L2B / 32.0f));
#pragma unroll
        for (int r = 0; r < 4; r++) {
            float pos = (float)(st * 64 + 16 * w + quad * 4 + r);
            float s1, c1, s2, c2;
            sincosf(pos * inv1, &s1, &c1);
            sincosf(pos * inv2, &s2, &c2);
            float a0 = acc[0][r], a1 = acc[1][r], a2 = acc[2][r], a3 = acc[3][r];
            acc[0][r] = a0 * c1 - a2 * s1;
            acc[1][r] = a1 * c2 - a3 * s2;
            acc[2][r] = a2 * c1 + a0 * s1;
            acc[3][r] = a3 * c2 + a1 * s2;
        }
        unsigned short* dst = (p == 0 ? Qw : Kw) + (((size_t)(b * NH + h)) * SEQ + st * 64) * DH;
#pragma unroll
        for (int nt = 0; nt < 4; nt++)
#pragma unroll
            for (int r = 0; r < 4; r++)
                dst[(16 * w + quad * 4 + r) * DH + 16 * nt + l] = f2bf(acc[nt][r]);
    } else {
        // V: transpose 64x64 tile via LDS, write [b][h][d][s]
#pragma unroll
        for (int nt = 0; nt < 4; nt++)
#pragma unroll
            for (int r = 0; r < 4; r++)
                sm[(16 * nt + l) * 72 + 16 * w + quad * 4 + r] = f2bf(acc[nt][r]);
        __syncthreads();
        int d = t >> 2, c = t & 3;
        ushort8 v0 = *(const ushort8*)&sm[d * 72 + c * 16];
        ushort8 v1 = *(const ushort8*)&sm[d * 72 + c * 16 + 8];
        unsigned short* dp = Vtw + (((size_t)(b * NH + h)) * DH + d) * SEQ + st * 64 + c * 16;
        *(ushort8*)dp = v0;
        *(ushort8*)(dp + 8) = v1;
    }
}

// ---------------------------------------------------------------------------
// Kernel B: causal flash attention per (b,h,64-row q-tile). Z -> bf16 [b][h][s][d]
// ---------------------------------------------------------------------------
__global__ __launch_bounds__(256) void kattn(
    const unsigned short* __restrict__ Qw, const unsigned short* __restrict__ Kw,
    const unsigned short* __restrict__ Vtw, unsigned short* __restrict__ Zw)
{
    __shared__ __align__(16) unsigned short sK[64 * 72];
    __shared__ __align__(16) unsigned short sV[64 * 72];
    __shared__ __align__(16) unsigned short sP[64 * 72];
    int bid = blockIdx.x;              // 768 = 2 * 12 * 32
    int b = bid / 384;
    int h = (bid / 32) % 12;
    int qt = 31 - (bid & 31);          // heavy tiles first
    int t = threadIdx.x;
    int w = t >> 6, lane = t & 63, l = lane & 15, quad = lane >> 4;
    int q0 = qt * 64;

    const unsigned short* qbase = Qw + (((size_t)(b * NH + h)) * SEQ + q0 + 16 * w + l) * DH;
    bf16x8 qf0 = ld_bf8(qbase + quad * 8);
    bf16x8 qf1 = ld_bf8(qbase + 32 + quad * 8);

    const unsigned short* kb = Kw + ((size_t)(b * NH + h)) * SEQ * DH;
    const unsigned short* vb = Vtw + ((size_t)(b * NH + h)) * DH * SEQ;

    int srow = t >> 2, sc = (t & 3) * 16;

    float m_i[4], l_i[4];
    f32x4 zacc[4] = {};
#pragma unroll
    for (int r = 0; r < 4; r++) { m_i[r] = -1e30f; l_i[r] = 0.0f; }

    for (int kt = 0; kt <= qt; kt++) {
        __syncthreads();   // protect LDS from previous iteration's readers
        {
            const unsigned short* ks = kb + (size_t)(kt * 64 + srow) * DH + sc;
            ushort8 a0 = *(const ushort8*)ks;
            ushort8 a1 = *(const ushort8*)(ks + 8);
            *(ushort8*)&sK[srow * 72 + sc] = a0;
            *(ushort8*)&sK[srow * 72 + sc + 8] = a1;
            const unsigned short* vs = vb + (size_t)srow * SEQ + kt * 64 + sc;
            ushort8 b0 = *(const ushort8*)vs;
            ushort8 b1 = *(const ushort8*)(vs + 8);
            *(ushort8*)&sV[srow * 72 + sc] = b0;
            *(ushort8*)&sV[srow * 72 + sc + 8] = b1;
        }
        __syncthreads();

        f32x4 sacc[4] = {};
#pragma unroll
        for (int nt = 0; nt < 4; nt++) {
            bf16x8 k0f = __builtin_bit_cast(bf16x8, *(const ushort8*)&sK[(16 * nt + l) * 72 + quad * 8]);
            sacc[nt] = __builtin_amdgcn_mfma_f32_16x16x32_bf16(qf0, k0f, sacc[nt], 0, 0, 0);
            bf16x8 k1f = __builtin_bit_cast(bf16x8, *(const ushort8*)&sK[(16 * nt + l) * 72 + 32 + quad * 8]);
            sacc[nt] = __builtin_amdgcn_mfma_f32_16x16x32_bf16(qf1, k1f, sacc[nt], 0, 0, 0);
        }
        bool diag = (kt == qt);
#pragma unroll
        for (int nt = 0; nt < 4; nt++)
#pragma unroll
            for (int r = 0; r < 4; r++) {
                float s = sacc[nt][r] * 0.125f;
                if (diag && (16 * nt + l) > (16 * w + quad * 4 + r)) s = -1e30f;
                sacc[nt][r] = s;
            }
        float newm[4], alpha[4];
#pragma unroll
        for (int r = 0; r < 4; r++) {
            float rm = fmaxf(fmaxf(sacc[0][r], sacc[1][r]), fmaxf(sacc[2][r], sacc[3][r]));
            rm = fmaxf(rm, __shfl_xor(rm, 1));
            rm = fmaxf(rm, __shfl_xor(rm, 2));
            rm = fmaxf(rm, __shfl_xor(rm, 4));
            rm = fmaxf(rm, __shfl_xor(rm, 8));
            float nm = fmaxf(m_i[r], rm);
            alpha[r] = __expf(m_i[r] - nm);
            m_i[r] = nm;
            newm[r] = nm;
        }
#pragma unroll
        for (int r = 0; r < 4; r++) {
            float rs = 0.0f;
#pragma unroll
            for (int nt = 0; nt < 4; nt++) {
                float pv = __expf(sacc[nt][r] - newm[r]);
                sacc[nt][r] = pv;
                rs += pv;
            }
            rs += __shfl_xor(rs, 1);
            rs += __shfl_xor(rs, 2);
            rs += __shfl_xor(rs, 4);
            rs += __shfl_xor(rs, 8);
            l_i[r] = l_i[r] * alpha[r] + rs;
            zacc[0][r] *= alpha[r]; zacc[1][r] *= alpha[r];
            zacc[2][r] *= alpha[r]; zacc[3][r] *= alpha[r];
        }
        // P: C-layout -> A-layout through per-wave LDS slice (rows [16w,16w+16))
#pragma unroll
        for (int nt = 0; nt < 4; nt++)
#pragma unroll
            for (int r = 0; r < 4; r++)
                sP[(w * 16 + quad * 4 + r) * 72 + 16 * nt + l] = f2bf(sacc[nt][r]);
        __asm__ volatile("s_waitcnt lgkmcnt(0)" ::: "memory");
        bf16x8 pa0 = __builtin_bit_cast(bf16x8, *(const ushort8*)&sP[(w * 16 + l) * 72 + quad * 8]);
        bf16x8 pa1 = __builtin_bit_cast(bf16x8, *(const ushort8*)&sP[(w * 16 + l) * 72 + 32 + quad * 8]);
#pragma unroll
        for (int nt = 0; nt < 4; nt++) {
            bf16x8 v0f = __builtin_bit_cast(bf16x8, *(const ushort8*)&sV[(16 * nt + l) * 72 + quad * 8]);
            zacc[nt] = __builtin_amdgcn_mfma_f32_16x16x32_bf16(pa0, v0f, zacc[nt], 0, 0, 0);
            bf16x8 v1f = __builtin_bit_cast(bf16x8, *(const ushort8*)&sV[(16 * nt + l) * 72 + 32 + quad * 8]);
            zacc[nt] = __builtin_amdgcn_mfma_f32_16x16x32_bf16(pa1, v1f, zacc[nt], 0, 0, 0);
        }
    }
    unsigned short* zb = Zw + (((size_t)(b * NH + h)) * SEQ + q0) * DH;
#pragma unroll
    for (int r = 0; r < 4; r++) {
        float inv = 1.0f / l_i[r];
#pragma unroll
        for (int nt = 0; nt < 4; nt++)
            zb[(16 * w + quad * 4 + r) * DH + 16 * nt + l] = f2bf(zacc[nt][r] * inv);
    }
}

// ---------------------------------------------------------------------------
// Kernel C: out[b][s][h][m] = Z[b][h][s][:] @ W_O[h] + b_O/12  (fp32 out)
// ---------------------------------------------------------------------------
__global__ __launch_bounds__(256) void kout(
    const unsigned short* __restrict__ Zw, const unsigned short* __restrict__ Wot,
    const float* __restrict__ bO, float* __restrict__ out)
{
    int bid = blockIdx.x;              // 768
    int b = bid / 384;
    int h = (bid / 32) % 12;
    int st = bid & 31;
    int t = threadIdx.x;
    int w = t >> 6, lane = t & 63, l = lane & 15, quad = lane >> 4;

    const unsigned short* zbase = Zw + (((size_t)(b * NH + h)) * SEQ + st * 64 + 16 * w + l) * DH;
    bf16x8 za0 = ld_bf8(zbase + quad * 8);
    bf16x8 za1 = ld_bf8(zbase + 32 + quad * 8);
    const unsigned short* wbase = Wot + (size_t)h * DM * DH;
    float* obase = out + ((size_t)(b * SEQ + st * 64) * NH + h) * DM;

    for (int chunk = 0; chunk < 6; chunk++) {
        f32x4 acc[8] = {};
#pragma unroll
        for (int nt = 0; nt < 8; nt++) {
            int m = chunk * 128 + 16 * nt + l;
            bf16x8 w0 = ld_bf8(wbase + (size_t)m * DH + quad * 8);
            acc[nt] = __builtin_amdgcn_mfma_f32_16x16x32_bf16(za0, w0, acc[nt], 0, 0, 0);
            bf16x8 w1 = ld_bf8(wbase + (size_t)m * DH + 32 + quad * 8);
            acc[nt] = __builtin_amdgcn_mfma_f32_16x16x32_bf16(za1, w1, acc[nt], 0, 0, 0);
        }
#pragma unroll
        for (int nt = 0; nt < 8; nt++) {
            int m = chunk * 128 + 16 * nt + l;
            float bo = bO[m] * (1.0f / 12.0f);
#pragma unroll
            for (int r = 0; r < 4; r++) {
                int srow = 16 * w + quad * 4 + r;
                obase[(size_t)srow * NH * DM + m] = acc[nt][r] + bo;
            }
        }
    }
}

extern "C" void kernel_launch(void* const* d_in, const int* in_sizes, int n_in,
                              void* d_out, int out_size, void* d_ws, size_t ws_size,
                              hipStream_t stream) {
    const float* Xq = (const float*)d_in[0];
    const float* Xk = (const float*)d_in[1];
    const float* Xv = (const float*)d_in[2];
    const float* WQ = (const float*)d_in[3];
    const float* bQ = (const float*)d_in[4];
    const float* WK = (const float*)d_in[5];
    const float* bK = (const float*)d_in[6];
    const float* WV = (const float*)d_in[7];
    const float* bV = (const float*)d_in[8];
    const float* WO = (const float*)d_in[9];
    const float* bO = (const float*)d_in[10];
    float* out = (float*)d_out;

    char* ws = (char*)d_ws;
    size_t o = 0;
    const size_t qkv_bytes = (size_t)NB * NH * SEQ * DH * 2;
    unsigned short* Qw  = (unsigned short*)(ws + o); o += qkv_bytes;
    unsigned short* Kw  = (unsigned short*)(ws + o); o += qkv_bytes;
    unsigned short* Vtw = (unsigned short*)(ws + o); o += qkv_bytes;
    unsigned short* Zw  = (unsigned short*)(ws + o); o += qkv_bytes;
    unsigned short* Wt  = (unsigned short*)(ws + o); o += (size_t)3 * NH * DH * DM * 2;
    unsigned short* Wot = (unsigned short*)(ws + o); o += (size_t)NH * DM * DH * 2;

    kprep<<<dim3(576), dim3(256), 0, stream>>>(WQ, WK, WV, WO, Wt, Wot);
    kproj<<<dim3(2304), dim3(256), 0, stream>>>(Xq, Xk, Xv, Wt, bQ, bK, bV, Qw, Kw, Vtw);
    kattn<<<dim3(768), dim3(256), 0, stream>>>(Qw, Kw, Vtw, Zw);
    kout<<<dim3(768), dim3(256), 0, stream>>>(Zw, Wot, bO, out);
}

// Round 2
// 627.485 us; speedup vs baseline: 1.0380x; 1.0380x over previous
//
#include <hip/hip_runtime.h>
#include <hip/hip_bf16.h>

typedef __bf16 bf16x8 __attribute__((ext_vector_type(8)));
typedef float f32x4 __attribute__((ext_vector_type(4)));
typedef unsigned short ushort8 __attribute__((ext_vector_type(8)));

static_assert(sizeof(bf16x8) == 16, "bf16x8 must be 16B");

#define NH 12
#define SEQ 2048
#define DM 768
#define DH 64
#define NB 2

static __device__ __forceinline__ unsigned short f2bf(float f) {
    __hip_bfloat16 h = __float2bfloat16(f);
    return __builtin_bit_cast(unsigned short, h);
}
static __device__ __forceinline__ bf16x8 ld_bf8(const unsigned short* p) {
    ushort8 u = *(const ushort8*)p;
    return __builtin_bit_cast(bf16x8, u);
}
static __device__ __forceinline__ bf16x8 pack8(float4 f0, float4 f1) {
    ushort8 u;
    u[0] = f2bf(f0.x); u[1] = f2bf(f0.y); u[2] = f2bf(f0.z); u[3] = f2bf(f0.w);
    u[4] = f2bf(f1.x); u[5] = f2bf(f1.y); u[6] = f2bf(f1.z); u[7] = f2bf(f1.w);
    return __builtin_bit_cast(bf16x8, u);
}

// ---------------------------------------------------------------------------
// Kernel D: weight transpose + bf16 convert.
// Wt[p][h][n=dh][k=dm] = W_p[h][k][n];  Wot[h][m][d] = W_O[h][d][m]
// ---------------------------------------------------------------------------
__global__ __launch_bounds__(256) void kprep(
    const float* __restrict__ WQ, const float* __restrict__ WK,
    const float* __restrict__ WV, const float* __restrict__ WO,
    unsigned short* __restrict__ Wt, unsigned short* __restrict__ Wot)
{
    __shared__ __align__(16) unsigned short T[64 * 72];
    int bid = blockIdx.x;              // 576 = 4 tensors * 12 h * 12 tiles
    int tensor = bid / 144;
    int rem = bid % 144;
    int h = rem / 12, tile = rem % 12;
    const float* src; unsigned short* dst; int R, C, r0, c0;
    if (tensor < 3) {
        src = (tensor == 0 ? WQ : tensor == 1 ? WK : WV) + (size_t)h * DM * DH;
        dst = Wt + ((size_t)tensor * NH + h) * DH * DM;
        R = DM; C = DH; r0 = tile * 64; c0 = 0;
    } else {
        src = WO + (size_t)h * DH * DM;
        dst = Wot + (size_t)h * DM * DH;
        R = DH; C = DM; r0 = 0; c0 = tile * 64;
    }
    int t = threadIdx.x;
    int rr = t >> 2, cc0 = (t & 3) * 16;
    const float* sp = src + (size_t)(r0 + rr) * C + c0 + cc0;
#pragma unroll
    for (int i = 0; i < 4; i++) {
        float4 v = *(const float4*)(sp + 4 * i);
        T[(cc0 + 4 * i + 0) * 72 + rr] = f2bf(v.x);
        T[(cc0 + 4 * i + 1) * 72 + rr] = f2bf(v.y);
        T[(cc0 + 4 * i + 2) * 72 + rr] = f2bf(v.z);
        T[(cc0 + 4 * i + 3) * 72 + rr] = f2bf(v.w);
    }
    __syncthreads();
    int cc = t >> 2, ch = t & 3;
    ushort8 o0 = *(const ushort8*)&T[cc * 72 + ch * 16];
    ushort8 o1 = *(const ushort8*)&T[cc * 72 + ch * 16 + 8];
    unsigned short* dp = dst + (size_t)(c0 + cc) * R + r0 + ch * 16;
    *(ushort8*)dp = o0;
    *(ushort8*)(dp + 8) = o1;
}

// ---------------------------------------------------------------------------
// Kernel A: QKV projection + bias + rotary; Q,K -> [b][h][s][d] bf16,
// V -> transposed [b][h][d][s] bf16.
// K-loop processes 128-col chunks with all X loads hoisted (8 in flight) to
// hide HBM latency; W fragments (L2-hot) hoisted 4 at a time.
// ---------------------------------------------------------------------------
__global__ __launch_bounds__(256) void kproj(
    const float* __restrict__ Xq, const float* __restrict__ Xk,
    const float* __restrict__ Xv, const unsigned short* __restrict__ Wt,
    const float* __restrict__ bQ, const float* __restrict__ bK,
    const float* __restrict__ bV,
    unsigned short* __restrict__ Qw, unsigned short* __restrict__ Kw,
    unsigned short* __restrict__ Vtw)
{
    __shared__ __align__(16) unsigned short sm[64 * 72];
    int bid = blockIdx.x;              // 2304 = 3 * 2 * 12 * 32
    int p  = bid / 768;
    int b  = (bid / 384) & 1;
    int h  = (bid / 32) % 12;
    int st = bid & 31;
    const float* X = p == 0 ? Xq : (p == 1 ? Xk : Xv);
    int t = threadIdx.x;
    int w = t >> 6, lane = t & 63, l = lane & 15, quad = lane >> 4;

    const float* xrow = X + (((size_t)(b * SEQ + st * 64 + 16 * w + l)) * NH + h) * DM + quad * 8;
    const unsigned short* wbase = Wt + ((size_t)(p * NH + h)) * DH * DM + (size_t)l * DM + quad * 8;

    f32x4 acc[4] = {};
    for (int k0 = 0; k0 < DM; k0 += 128) {
        float4 xa[8];
#pragma unroll
        for (int u = 0; u < 4; u++) {
            xa[2 * u]     = *(const float4*)(xrow + k0 + 32 * u);
            xa[2 * u + 1] = *(const float4*)(xrow + k0 + 32 * u + 4);
        }
#pragma unroll
        for (int u = 0; u < 4; u++) {
            bf16x8 wf[4];
#pragma unroll
            for (int nt = 0; nt < 4; nt++)
                wf[nt] = ld_bf8(wbase + (size_t)nt * 16 * DM + k0 + 32 * u);
            bf16x8 a = pack8(xa[2 * u], xa[2 * u + 1]);
#pragma unroll
            for (int nt = 0; nt < 4; nt++)
                acc[nt] = __builtin_amdgcn_mfma_f32_16x16x32_bf16(a, wf[nt], acc[nt], 0, 0, 0);
        }
    }

    const float* bias = p == 0 ? bQ : (p == 1 ? bK : bV);
#pragma unroll
    for (int nt = 0; nt < 4; nt++) {
        float bv = bias[h * DH + 16 * nt + l];
#pragma unroll
        for (int r = 0; r < 4; r++) acc[nt][r] += bv;
    }

    if (p < 2) {
        // rotary: d and d+32 live in acc[nt] and acc[nt+2] at the same lane/reg
        const float L2B = 13.287712379549449f;   // log2(10000)
        float inv1 = exp2f(-((float)l)        * (L2B / 32.0f));
        float inv2 = exp2f(-((float)(l + 16)) * (L2B / 32.0f));
#pragma unroll
        for (int r = 0; r < 4; r++) {
            float pos = (float)(st * 64 + 16 * w + quad * 4 + r);
            float s1, c1, s2, c2;
            sincosf(pos * inv1, &s1, &c1);
            sincosf(pos * inv2, &s2, &c2);
            float a0 = acc[0][r], a1 = acc[1][r], a2 = acc[2][r], a3 = acc[3][r];
            acc[0][r] = a0 * c1 - a2 * s1;
            acc[1][r] = a1 * c2 - a3 * s2;
            acc[2][r] = a2 * c1 + a0 * s1;
            acc[3][r] = a3 * c2 + a1 * s2;
        }
        // repack C-layout -> row-major via wave-local LDS slice, then 16B stores
#pragma unroll
        for (int nt = 0; nt < 4; nt++)
#pragma unroll
            for (int r = 0; r < 4; r++)
                sm[(16 * w + quad * 4 + r) * 72 + 16 * nt + l] = f2bf(acc[nt][r]);
        __asm__ volatile("s_waitcnt lgkmcnt(0)" ::: "memory");
        int local = t & 63;
        int row = 16 * w + (local >> 2), c = local & 3;
        ushort8 q0 = *(const ushort8*)&sm[row * 72 + c * 16];
        ushort8 q1 = *(const ushort8*)&sm[row * 72 + c * 16 + 8];
        unsigned short* dst = (p == 0 ? Qw : Kw) + (((size_t)(b * NH + h)) * SEQ + st * 64 + row) * DH + c * 16;
        *(ushort8*)dst = q0;
        *(ushort8*)(dst + 8) = q1;
    } else {
        // V: transpose 64x64 tile via LDS, write [b][h][d][s]
#pragma unroll
        for (int nt = 0; nt < 4; nt++)
#pragma unroll
            for (int r = 0; r < 4; r++)
                sm[(16 * nt + l) * 72 + 16 * w + quad * 4 + r] = f2bf(acc[nt][r]);
        __syncthreads();
        int d = t >> 2, c = t & 3;
        ushort8 v0 = *(const ushort8*)&sm[d * 72 + c * 16];
        ushort8 v1 = *(const ushort8*)&sm[d * 72 + c * 16 + 8];
        unsigned short* dp = Vtw + (((size_t)(b * NH + h)) * DH + d) * SEQ + st * 64 + c * 16;
        *(ushort8*)dp = v0;
        *(ushort8*)(dp + 8) = v1;
    }
}

// ---------------------------------------------------------------------------
// Kernel B: causal flash attention per (b,h,64-row q-tile). Z -> bf16 [b][h][s][d]
// Register-prefetch double buffer: kt+1's global K/V loads issue right after
// the post-store barrier and complete during kt's softmax/MFMA body.
// ---------------------------------------------------------------------------
__global__ __launch_bounds__(256) void kattn(
    const unsigned short* __restrict__ Qw, const unsigned short* __restrict__ Kw,
    const unsigned short* __restrict__ Vtw, unsigned short* __restrict__ Zw)
{
    __shared__ __align__(16) unsigned short sK[64 * 72];
    __shared__ __align__(16) unsigned short sV[64 * 72];
    __shared__ __align__(16) unsigned short sP[64 * 72];
    int bid = blockIdx.x;              // 768 = 2 * 12 * 32
    int b = bid / 384;
    int h = (bid / 32) % 12;
    int qt = 31 - (bid & 31);          // heavy tiles first
    int t = threadIdx.x;
    int w = t >> 6, lane = t & 63, l = lane & 15, quad = lane >> 4;
    int q0 = qt * 64;

    const unsigned short* qbase = Qw + (((size_t)(b * NH + h)) * SEQ + q0 + 16 * w + l) * DH;
    bf16x8 qf0 = ld_bf8(qbase + quad * 8);
    bf16x8 qf1 = ld_bf8(qbase + 32 + quad * 8);

    const unsigned short* kb = Kw + ((size_t)(b * NH + h)) * SEQ * DH;
    const unsigned short* vb = Vtw + ((size_t)(b * NH + h)) * DH * SEQ;

    int srow = t >> 2, sc = (t & 3) * 16;

    float m_i[4], l_i[4];
    f32x4 zacc[4] = {};
#pragma unroll
    for (int r = 0; r < 4; r++) { m_i[r] = -1e30f; l_i[r] = 0.0f; }

    // prefetch tile 0
    ushort8 pk0, pk1, pv0, pv1;
    {
        const unsigned short* ks = kb + (size_t)srow * DH + sc;
        pk0 = *(const ushort8*)ks;
        pk1 = *(const ushort8*)(ks + 8);
        const unsigned short* vs = vb + (size_t)srow * SEQ + sc;
        pv0 = *(const ushort8*)vs;
        pv1 = *(const ushort8*)(vs + 8);
    }

    for (int kt = 0; kt <= qt; kt++) {
        // store prefetched tile to LDS (previous iteration's readers finished
        // at the barrier at the end of the loop body)
        *(ushort8*)&sK[srow * 72 + sc] = pk0;
        *(ushort8*)&sK[srow * 72 + sc + 8] = pk1;
        *(ushort8*)&sV[srow * 72 + sc] = pv0;
        *(ushort8*)&sV[srow * 72 + sc + 8] = pv1;
        __syncthreads();
        if (kt < qt) {
            const unsigned short* ks = kb + (size_t)((kt + 1) * 64 + srow) * DH + sc;
            pk0 = *(const ushort8*)ks;
            pk1 = *(const ushort8*)(ks + 8);
            const unsigned short* vs = vb + (size_t)srow * SEQ + (kt + 1) * 64 + sc;
            pv0 = *(const ushort8*)vs;
            pv1 = *(const ushort8*)(vs + 8);
        }

        f32x4 sacc[4] = {};
#pragma unroll
        for (int nt = 0; nt < 4; nt++) {
            bf16x8 k0f = __builtin_bit_cast(bf16x8, *(const ushort8*)&sK[(16 * nt + l) * 72 + quad * 8]);
            sacc[nt] = __builtin_amdgcn_mfma_f32_16x16x32_bf16(qf0, k0f, sacc[nt], 0, 0, 0);
            bf16x8 k1f = __builtin_bit_cast(bf16x8, *(const ushort8*)&sK[(16 * nt + l) * 72 + 32 + quad * 8]);
            sacc[nt] = __builtin_amdgcn_mfma_f32_16x16x32_bf16(qf1, k1f, sacc[nt], 0, 0, 0);
        }
        bool diag = (kt == qt);
#pragma unroll
        for (int nt = 0; nt < 4; nt++)
#pragma unroll
            for (int r = 0; r < 4; r++) {
                float s = sacc[nt][r] * 0.125f;
                if (diag && (16 * nt + l) > (16 * w + quad * 4 + r)) s = -1e30f;
                sacc[nt][r] = s;
            }
        float newm[4], alpha[4];
#pragma unroll
        for (int r = 0; r < 4; r++) {
            float rm = fmaxf(fmaxf(sacc[0][r], sacc[1][r]), fmaxf(sacc[2][r], sacc[3][r]));
            rm = fmaxf(rm, __shfl_xor(rm, 1));
            rm = fmaxf(rm, __shfl_xor(rm, 2));
            rm = fmaxf(rm, __shfl_xor(rm, 4));
            rm = fmaxf(rm, __shfl_xor(rm, 8));
            float nm = fmaxf(m_i[r], rm);
            alpha[r] = __expf(m_i[r] - nm);
            m_i[r] = nm;
            newm[r] = nm;
        }
#pragma unroll
        for (int r = 0; r < 4; r++) {
            float rs = 0.0f;
#pragma unroll
            for (int nt = 0; nt < 4; nt++) {
                float pv = __expf(sacc[nt][r] - newm[r]);
                sacc[nt][r] = pv;
                rs += pv;
            }
            rs += __shfl_xor(rs, 1);
            rs += __shfl_xor(rs, 2);
            rs += __shfl_xor(rs, 4);
            rs += __shfl_xor(rs, 8);
            l_i[r] = l_i[r] * alpha[r] + rs;
            zacc[0][r] *= alpha[r]; zacc[1][r] *= alpha[r];
            zacc[2][r] *= alpha[r]; zacc[3][r] *= alpha[r];
        }
        // P: C-layout -> A-layout through per-wave LDS slice (rows [16w,16w+16))
#pragma unroll
        for (int nt = 0; nt < 4; nt++)
#pragma unroll
            for (int r = 0; r < 4; r++)
                sP[(w * 16 + quad * 4 + r) * 72 + 16 * nt + l] = f2bf(sacc[nt][r]);
        __asm__ volatile("s_waitcnt lgkmcnt(0)" ::: "memory");
        bf16x8 pa0 = __builtin_bit_cast(bf16x8, *(const ushort8*)&sP[(w * 16 + l) * 72 + quad * 8]);
        bf16x8 pa1 = __builtin_bit_cast(bf16x8, *(const ushort8*)&sP[(w * 16 + l) * 72 + 32 + quad * 8]);
#pragma unroll
        for (int nt = 0; nt < 4; nt++) {
            bf16x8 v0f = __builtin_bit_cast(bf16x8, *(const ushort8*)&sV[(16 * nt + l) * 72 + quad * 8]);
            zacc[nt] = __builtin_amdgcn_mfma_f32_16x16x32_bf16(pa0, v0f, zacc[nt], 0, 0, 0);
            bf16x8 v1f = __builtin_bit_cast(bf16x8, *(const ushort8*)&sV[(16 * nt + l) * 72 + 32 + quad * 8]);
            zacc[nt] = __builtin_amdgcn_mfma_f32_16x16x32_bf16(pa1, v1f, zacc[nt], 0, 0, 0);
        }
        __syncthreads();  // compute readers done before next store
    }
    unsigned short* zb = Zw + (((size_t)(b * NH + h)) * SEQ + q0) * DH;
#pragma unroll
    for (int r = 0; r < 4; r++) {
        float inv = 1.0f / l_i[r];
#pragma unroll
        for (int nt = 0; nt < 4; nt++)
            zb[(16 * w + quad * 4 + r) * DH + 16 * nt + l] = f2bf(zacc[nt][r] * inv);
    }
}

// ---------------------------------------------------------------------------
// Kernel C: out[b][s][h][m] = Z[b][h][s][:] @ W_O[h] + b_O/12  (fp32 out)
// One 128-col chunk per block (TLP instead of a sequential 6-chunk loop).
// ---------------------------------------------------------------------------
__global__ __launch_bounds__(256) void kout(
    const unsigned short* __restrict__ Zw, const unsigned short* __restrict__ Wot,
    const float* __restrict__ bO, float* __restrict__ out)
{
    int bid = blockIdx.x;              // 4608 = 768 * 6
    int chunk = bid % 6;
    int bh = bid / 6;
    int b = bh / 384;
    int h = (bh / 32) % 12;
    int st = bh & 31;
    int t = threadIdx.x;
    int w = t >> 6, lane = t & 63, l = lane & 15, quad = lane >> 4;

    const unsigned short* zbase = Zw + (((size_t)(b * NH + h)) * SEQ + st * 64 + 16 * w + l) * DH;
    bf16x8 za0 = ld_bf8(zbase + quad * 8);
    bf16x8 za1 = ld_bf8(zbase + 32 + quad * 8);
    const unsigned short* wbase = Wot + (size_t)h * DM * DH + (size_t)(chunk * 128 + l) * DH + quad * 8;
    float* obase = out + ((size_t)(b * SEQ + st * 64) * NH + h) * DM + chunk * 128;

    f32x4 acc[8] = {};
#pragma unroll
    for (int nt = 0; nt < 8; nt++) {
        bf16x8 w0 = ld_bf8(wbase + (size_t)nt * 16 * DH);
        acc[nt] = __builtin_amdgcn_mfma_f32_16x16x32_bf16(za0, w0, acc[nt], 0, 0, 0);
        bf16x8 w1 = ld_bf8(wbase + (size_t)nt * 16 * DH + 32);
        acc[nt] = __builtin_amdgcn_mfma_f32_16x16x32_bf16(za1, w1, acc[nt], 0, 0, 0);
    }
#pragma unroll
    for (int nt = 0; nt < 8; nt++) {
        int m = 16 * nt + l;
        float bo = bO[chunk * 128 + m] * (1.0f / 12.0f);
#pragma unroll
        for (int r = 0; r < 4; r++) {
            int srow = 16 * w + quad * 4 + r;
            obase[(size_t)srow * NH * DM + m] = acc[nt][r] + bo;
        }
    }
}

extern "C" void kernel_launch(void* const* d_in, const int* in_sizes, int n_in,
                              void* d_out, int out_size, void* d_ws, size_t ws_size,
                              hipStream_t stream) {
    const float* Xq = (const float*)d_in[0];
    const float* Xk = (const float*)d_in[1];
    const float* Xv = (const float*)d_in[2];
    const float* WQ = (const float*)d_in[3];
    const float* bQ = (const float*)d_in[4];
    const float* WK = (const float*)d_in[5];
    const float* bK = (const float*)d_in[6];
    const float* WV = (const float*)d_in[7];
    const float* bV = (const float*)d_in[8];
    const float* WO = (const float*)d_in[9];
    const float* bO = (const float*)d_in[10];
    float* out = (float*)d_out;

    char* ws = (char*)d_ws;
    size_t o = 0;
    const size_t qkv_bytes = (size_t)NB * NH * SEQ * DH * 2;
    unsigned short* Qw  = (unsigned short*)(ws + o); o += qkv_bytes;
    unsigned short* Kw  = (unsigned short*)(ws + o); o += qkv_bytes;
    unsigned short* Vtw = (unsigned short*)(ws + o); o += qkv_bytes;
    unsigned short* Zw  = (unsigned short*)(ws + o); o += qkv_bytes;
    unsigned short* Wt  = (unsigned short*)(ws + o); o += (size_t)3 * NH * DH * DM * 2;
    unsigned short* Wot = (unsigned short*)(ws + o); o += (size_t)NH * DM * DH * 2;

    kprep<<<dim3(576), dim3(256), 0, stream>>>(WQ, WK, WV, WO, Wt, Wot);
    kproj<<<dim3(2304), dim3(256), 0, stream>>>(Xq, Xk, Xv, Wt, bQ, bK, bV, Qw, Kw, Vtw);
    kattn<<<dim3(768), dim3(256), 0, stream>>>(Qw, Kw, Vtw, Zw);
    kout<<<dim3(4608), dim3(256), 0, stream>>>(Zw, Wot, bO, out);
}